// Round 1
// baseline (547.377 us; speedup 1.0000x reference)
//
#include <hip/hip_runtime.h>
#include <math.h>
#include <string.h>

// Problem constants (from reference)
#define BB 4
#define SS 1024
#define HH 32
#define GG 8       // kv heads
#define DD 128
#define NTOK (BB*SS)
#define NBLK 32
#define BLKSZ 256

typedef __attribute__((ext_vector_type(8)))  short  short8;   // 8 bf16 = 4 VGPRs (MFMA A/B operand)
typedef __attribute__((ext_vector_type(16))) float  floatx16; // MFMA C/D

union FragU { unsigned u[4]; uint4 u4; short8 s8; };

// round-to-nearest-even f32 -> bf16, packed pair
__device__ __forceinline__ unsigned pack_bf16x2(float a, float b) {
    unsigned ua = __builtin_bit_cast(unsigned, a);
    unsigned ub = __builtin_bit_cast(unsigned, b);
    ua = (ua + 0x7FFFu + ((ua >> 16) & 1u)) >> 16;
    ub = (ub + 0x7FFFu + ((ub >> 16) & 1u)) & 0xFFFF0000u;
    return ua | ub;
}

// ---------------- prepass: k (f32) -> kb (bf16, same [tok][g][d] layout) ----------------
__global__ void cvt_k_kernel(const float* __restrict__ k, uint2* __restrict__ kb) {
    size_t i = (size_t)blockIdx.x * 256 + threadIdx.x;   // one float4 -> uint2 (4 bf16)
    float4 f = ((const float4*)k)[i];
    uint2 o; o.x = pack_bf16x2(f.x, f.y); o.y = pack_bf16x2(f.z, f.w);
    kb[i] = o;
}

// ---------------- prepass: v (f32 [tok][g][d]) -> vt (bf16 [(b*G+g)*D + d][s]) ----------------
__global__ void transpose_v_kernel(const float* __restrict__ v, unsigned short* __restrict__ vt) {
    __shared__ float lds[64 * 129];               // 64 tokens x 128 d, pad 129 (bank-conflict-free)
    const int t  = threadIdx.x;
    const int s0 = blockIdx.x * 64, g = blockIdx.y, b = blockIdx.z;
    const int sl = t >> 2, cq = t & 3;
    const float* vp = v + ((size_t)(b * SS + s0 + sl) * GG + g) * DD;
    #pragma unroll
    for (int kk = 0; kk < 8; ++kk) {
        int chunk = cq + kk * 4;                  // 32 float4-chunks per row
        float4 f = *(const float4*)(vp + chunk * 4);
        float* lp = &lds[sl * 129 + chunk * 4];
        lp[0] = f.x; lp[1] = f.y; lp[2] = f.z; lp[3] = f.w;
    }
    __syncthreads();
    const int d = t >> 1, sh = t & 1;             // each thread: one d-row, 32 s values
    unsigned w[16];
    #pragma unroll
    for (int i = 0; i < 16; ++i) {
        float a = lds[(sh * 32 + 2 * i    ) * 129 + d];
        float c = lds[(sh * 32 + 2 * i + 1) * 129 + d];
        w[i] = pack_bf16x2(a, c);
    }
    unsigned* op = (unsigned*)(vt + ((size_t)(b * GG + g) * DD + d) * SS + s0 + sh * 32);
    #pragma unroll
    for (int i = 0; i < 4; ++i)
        ((uint4*)op)[i] = make_uint4(w[4*i], w[4*i+1], w[4*i+2], w[4*i+3]);
}

// ---------------- cache scatter (after d2d copy of input caches) ----------------
__global__ void scatter_kernel(const float* __restrict__ k, const float* __restrict__ v,
                               const int* __restrict__ slot_mapping,
                               float* __restrict__ kco, float* __restrict__ vco) {
    const int tok = blockIdx.x, c = threadIdx.x;  // 256 float4 per token row (G*D = 1024 f32)
    const int slot = slot_mapping[tok];
    if (slot < 0 || slot >= NBLK * BLKSZ) return; // matches reference's drop semantics
    float4 kf = ((const float4*)(k + (size_t)tok * 1024))[c];
    float4 vf = ((const float4*)(v + (size_t)tok * 1024))[c];
    ((float4*)(kco + (size_t)slot * 1024))[c] = kf;
    ((float4*)(vco + (size_t)slot * 1024))[c] = vf;
}

// ---------------- fused causal GQA flash attention ----------------
// block = 4 waves = 4 q-heads of one kv group; wave handles 32 q rows.
// S^T = K*Q^T (32x32x16 bf16 MFMA) -> softmax per q (= lane&31) -> O^T += V^T * P^T.
__global__ __launch_bounds__(256, 2)
void attn_kernel(const float* __restrict__ q,
                 const unsigned short* __restrict__ kb,   // bf16 [tok][g][d]
                 const unsigned short* __restrict__ vt,   // bf16 [(b*G+g)*D + d][s]
                 float* __restrict__ out, float sc2 /* bf16(1/sqrt(D)) * log2(e) */) {
    const int lane = threadIdx.x & 63;
    const int wave = threadIdx.x >> 6;
    const int l31  = lane & 31;
    const int hb   = lane >> 5;
    const int qt = blockIdx.x, g = blockIdx.y, b = blockIdx.z;
    const int h  = g * 4 + wave;
    const int q0 = qt * 32;
    const int tb = b * SS;

    // Q fragments (B operand of S^T): lane holds Q[q=l31][d = 16s + 8hb + j]
    short8 qf[8];
    const float* qp = q + ((size_t)(tb + q0 + l31) * HH + h) * DD;
    #pragma unroll
    for (int s = 0; s < 8; ++s) {
        int d0 = s * 16 + hb * 8;
        float4 f0 = *(const float4*)(qp + d0);
        float4 f1 = *(const float4*)(qp + d0 + 4);
        FragU fr;
        fr.u[0] = pack_bf16x2(f0.x, f0.y); fr.u[1] = pack_bf16x2(f0.z, f0.w);
        fr.u[2] = pack_bf16x2(f1.x, f1.y); fr.u[3] = pack_bf16x2(f1.z, f1.w);
        qf[s] = fr.s8;
    }

    floatx16 oacc[4] = {};            // O^T: 4 d-tiles of 32, col q = l31  (64 acc regs)
    float m = -__builtin_inff(), l = 0.f;

    const unsigned short* kbase = kb + ((size_t)tb * GG + g) * DD;       // + key*G*D
    const unsigned short* vbase = vt + (size_t)(b * GG + g) * DD * SS;   // + d*S + s

    for (int kt = 0; kt <= qt; ++kt) {
        const int k0 = kt * 32;
        // S^T tile: A = K (m=key=l31, k=d chunk), B = Q^T
        floatx16 st = {};
        const unsigned short* kp = kbase + (size_t)(k0 + l31) * (GG * DD) + hb * 8;
        #pragma unroll
        for (int s = 0; s < 8; ++s) {
            FragU kf; kf.u4 = *(const uint4*)(kp + s * 16);
            st = __builtin_amdgcn_mfma_f32_32x32x16_bf16(kf.s8, qf[s], st, 0, 0, 0);
        }
        // online softmax over keys (rows of S^T); per-lane q = l31, 16 keys here + 16 in lane^32
        float e[16], tmax = -__builtin_inff();
        #pragma unroll
        for (int r = 0; r < 16; ++r) {
            float val = st[r] * sc2;                       // exp2 domain
            if (kt == qt) {
                int row = (r & 3) + 8 * (r >> 2) + 4 * hb; // key_local
                if (row > l31) val = -__builtin_inff();    // causal mask (ref's clip(-100) ~ 0 contribution)
            }
            e[r] = val;
            tmax = fmaxf(tmax, val);
        }
        tmax = fmaxf(tmax, __shfl_xor(tmax, 32));
        const float mnew  = fmaxf(m, tmax);
        const float alpha = exp2f(m - mnew);
        m = mnew;
        float p[16], psum = 0.f;
        #pragma unroll
        for (int r = 0; r < 16; ++r) { p[r] = exp2f(e[r] - mnew); psum += p[r]; }
        psum += __shfl_xor(psum, 32);
        l = l * alpha + psum;
        #pragma unroll
        for (int t = 0; t < 4; ++t)
            #pragma unroll
            for (int r = 0; r < 16; ++r) oacc[t][r] *= alpha;
        // P -> bf16 pairs; cross-half swap builds B-operand (P^T) k-chunks
        unsigned pk[8], px[8];
        #pragma unroll
        for (int u2 = 0; u2 < 8; ++u2) pk[u2] = pack_bf16x2(p[2*u2], p[2*u2+1]);
        #pragma unroll
        for (int u2 = 0; u2 < 8; ++u2) px[u2] = (unsigned)__shfl_xor((int)pk[u2], 32);
        // O^T += V^T * P^T  (two k-steps of 16 keys, 4 d-tiles)
        #pragma unroll
        for (int s2 = 0; s2 < 2; ++s2) {
            FragU pf;
            if (hb == 0) { pf.u[0]=pk[4*s2  ]; pf.u[1]=pk[4*s2+1]; pf.u[2]=px[4*s2  ]; pf.u[3]=px[4*s2+1]; }
            else         { pf.u[0]=px[4*s2+2]; pf.u[1]=px[4*s2+3]; pf.u[2]=pk[4*s2+2]; pf.u[3]=pk[4*s2+3]; }
            const int key0 = k0 + s2 * 16 + hb * 8;
            #pragma unroll
            for (int t = 0; t < 4; ++t) {
                FragU vf; vf.u4 = *(const uint4*)(vbase + (size_t)(t * 32 + l31) * SS + key0);
                oacc[t] = __builtin_amdgcn_mfma_f32_32x32x16_bf16(vf.s8, pf.s8, oacc[t], 0, 0, 0);
            }
        }
    }
    // epilogue: normalize (state and O^T both keyed by q = l31 -> pure per-lane) and store
    const float inv_l = 1.f / l;
    float* op = out + ((size_t)(tb + q0 + l31) * HH + h) * DD;
    #pragma unroll
    for (int t = 0; t < 4; ++t) {
        #pragma unroll
        for (int grp = 0; grp < 4; ++grp) {
            float4 o4;
            o4.x = oacc[t][grp*4+0] * inv_l; o4.y = oacc[t][grp*4+1] * inv_l;
            o4.z = oacc[t][grp*4+2] * inv_l; o4.w = oacc[t][grp*4+3] * inv_l;
            *(float4*)(op + t * 32 + grp * 8 + hb * 4) = o4;  // d = 32t + 8grp + 4hb + 0..3
        }
    }
}

extern "C" void kernel_launch(void* const* d_in, const int* in_sizes, int n_in,
                              void* d_out, int out_size, void* d_ws, size_t ws_size,
                              hipStream_t stream) {
    const float* q     = (const float*)d_in[0];
    const float* k     = (const float*)d_in[1];
    const float* v     = (const float*)d_in[2];
    const float* kc_in = (const float*)d_in[3];
    const float* vc_in = (const float*)d_in[4];
    const int*   slot  = (const int*)d_in[5];

    float* o_out  = (float*)d_out;                               // [4096][4096]
    float* kc_out = o_out + (size_t)NTOK * HH * DD;              // [32][256][8][128]
    float* vc_out = kc_out + (size_t)NBLK * BLKSZ * GG * DD;

    unsigned short* kb = (unsigned short*)d_ws;                  // 8.4 MB
    unsigned short* vt = kb + (size_t)NTOK * GG * DD;            // 8.4 MB

    // scale = f32(bf16(1/sqrt(D))), folded with log2(e) for exp2-domain softmax
    float sc = 1.0f / sqrtf((float)DD);
    unsigned u; memcpy(&u, &sc, 4);
    u = (u + 0x7FFFu + ((u >> 16) & 1u)) & 0xFFFF0000u;
    memcpy(&sc, &u, 4);
    const float sc2 = sc * 1.44269504088896340736f;

    cvt_k_kernel<<<4096, 256, 0, stream>>>(k, (uint2*)kb);
    transpose_v_kernel<<<dim3(16, 8, 4), 256, 0, stream>>>(v, vt);
    hipMemcpyAsync(kc_out, kc_in, (size_t)NBLK * BLKSZ * GG * DD * 4, hipMemcpyDeviceToDevice, stream);
    hipMemcpyAsync(vc_out, vc_in, (size_t)NBLK * BLKSZ * GG * DD * 4, hipMemcpyDeviceToDevice, stream);
    scatter_kernel<<<NTOK, 256, 0, stream>>>(k, v, slot, kc_out, vc_out);
    attn_kernel<<<dim3(SS / 32, GG, BB), 256, 0, stream>>>(q, kb, vt, o_out, sc2);
}

// Round 2
// 462.304 us; speedup vs baseline: 1.1840x; 1.1840x over previous
//
#include <hip/hip_runtime.h>
#include <math.h>
#include <string.h>

// Problem constants (from reference)
#define BB 4
#define SS 1024
#define HH 32
#define GG 8       // kv heads
#define DD 128
#define NTOK (BB*SS)
#define NBLK 32
#define BLKSZ 256
#define CACHE_ELEMS ((size_t)NBLK*BLKSZ*GG*DD)   // 8.39M f32 per cache

typedef __attribute__((ext_vector_type(8)))  short  short8;   // 8 bf16 = 4 VGPRs (MFMA A/B operand)
typedef __attribute__((ext_vector_type(16))) float  floatx16; // MFMA C/D

union FragU { unsigned u[4]; uint4 u4; short8 s8; };

// round-to-nearest-even f32 -> bf16, packed pair
__device__ __forceinline__ unsigned pack_bf16x2(float a, float b) {
    unsigned ua = __builtin_bit_cast(unsigned, a);
    unsigned ub = __builtin_bit_cast(unsigned, b);
    ua = (ua + 0x7FFFu + ((ua >> 16) & 1u)) >> 16;
    ub = (ub + 0x7FFFu + ((ub >> 16) & 1u)) & 0xFFFF0000u;
    return ua | ub;
}

// ---------------- prepass: K -> fragment-swizzled bf16 ----------------
// dst unit (16B) index: (((b*G + g)*32 + kt)*8 + s)*64 + lane
// unit content: bf16 K[b*S + kt*32 + (lane&31)][g][s*16 + (lane>>5)*8 + 0..7]
__global__ void swizzle_k(const float* __restrict__ k, uint4* __restrict__ dst) {
    __shared__ float lds[32 * 132];
    const int t = threadIdx.x;
    const int kt = blockIdx.x, g = blockIdx.y, b = blockIdx.z;
    const float* sp = k + ((size_t)(b * SS + kt * 32) * GG + g) * DD;
    #pragma unroll
    for (int i = 0; i < 4; ++i) {
        int u = t + 256 * i;                  // 1024 float4 units: row = u>>5, c4 = u&31
        int row = u >> 5, c4 = u & 31;
        float4 f = *(const float4*)(sp + (size_t)row * (GG * DD) + c4 * 4);
        float* lp = &lds[row * 132 + c4 * 4];
        lp[0] = f.x; lp[1] = f.y; lp[2] = f.z; lp[3] = f.w;
    }
    __syncthreads();
    const int lane = t & 63, hb = lane >> 5, l31 = lane & 31;
    const size_t tbase = ((size_t)(b * GG + g) * 32 + kt) * 8;
    #pragma unroll
    for (int i = 0; i < 2; ++i) {
        int s = (t >> 6) + 4 * i;             // s in 0..7
        const float* lp = &lds[l31 * 132 + s * 16 + hb * 8];
        uint4 o;
        o.x = pack_bf16x2(lp[0], lp[1]); o.y = pack_bf16x2(lp[2], lp[3]);
        o.z = pack_bf16x2(lp[4], lp[5]); o.w = pack_bf16x2(lp[6], lp[7]);
        dst[(tbase + s) * 64 + lane] = o;
    }
}

// ---------------- prepass: V -> V^T fragment-swizzled bf16 ----------------
// dst unit index: (((b*G + g)*32 + kt)*8 + (t4*2 + s2))*64 + lane
// content: bf16 pairs of V[b*S + kt*32 + s2*16 + (lane>>5)*8 + j][g][t4*32 + (lane&31)]
__global__ void swizzle_v(const float* __restrict__ v, uint4* __restrict__ dst) {
    __shared__ float lds[32 * 132];
    const int t = threadIdx.x;
    const int kt = blockIdx.x, g = blockIdx.y, b = blockIdx.z;
    const float* sp = v + ((size_t)(b * SS + kt * 32) * GG + g) * DD;
    #pragma unroll
    for (int i = 0; i < 4; ++i) {
        int u = t + 256 * i;
        int row = u >> 5, c4 = u & 31;
        float4 f = *(const float4*)(sp + (size_t)row * (GG * DD) + c4 * 4);
        float* lp = &lds[row * 132 + c4 * 4];
        lp[0] = f.x; lp[1] = f.y; lp[2] = f.z; lp[3] = f.w;
    }
    __syncthreads();
    const int lane = t & 63, hb = lane >> 5, l31 = lane & 31;
    const size_t tbase = ((size_t)(b * GG + g) * 32 + kt) * 8;
    #pragma unroll
    for (int i = 0; i < 2; ++i) {
        int f8 = (t >> 6) + 4 * i;            // t4*2 + s2, 0..7
        int t4 = f8 >> 1, s2 = f8 & 1;
        int keyb = s2 * 16 + hb * 8;
        int d = t4 * 32 + l31;
        uint4 o;
        o.x = pack_bf16x2(lds[(keyb + 0) * 132 + d], lds[(keyb + 1) * 132 + d]);
        o.y = pack_bf16x2(lds[(keyb + 2) * 132 + d], lds[(keyb + 3) * 132 + d]);
        o.z = pack_bf16x2(lds[(keyb + 4) * 132 + d], lds[(keyb + 5) * 132 + d]);
        o.w = pack_bf16x2(lds[(keyb + 6) * 132 + d], lds[(keyb + 7) * 132 + d]);
        dst[(tbase + f8) * 64 + lane] = o;
    }
}

// ---------------- cache copy (replaces SDMA memcpy) ----------------
__global__ void copy_cache(const float4* __restrict__ s, float4* __restrict__ d) {
    size_t i = (size_t)blockIdx.x * 256 + threadIdx.x;
    d[i] = s[i];
}

// ---------------- cache scatter ----------------
__global__ void scatter_kernel(const float* __restrict__ k, const float* __restrict__ v,
                               const int* __restrict__ slot_mapping,
                               float* __restrict__ kco, float* __restrict__ vco) {
    const int tok = blockIdx.x, c = threadIdx.x;  // 256 float4 per token row (G*D = 1024 f32)
    const int slot = slot_mapping[tok];
    if (slot < 0 || slot >= NBLK * BLKSZ) return;
    float4 kf = ((const float4*)(k + (size_t)tok * 1024))[c];
    float4 vf = ((const float4*)(v + (size_t)tok * 1024))[c];
    ((float4*)(kco + (size_t)slot * 1024))[c] = kf;
    ((float4*)(vco + (size_t)slot * 1024))[c] = vf;
}

// ---------------- fused causal GQA flash attention ----------------
// block = 4 waves = 4 q-heads of one kv group; wave handles 32 q rows.
// S^T = K*Q^T (32x32x16 bf16 MFMA) -> softmax per q (= lane&31) -> O^T += V^T * P^T.
// K/V come pre-swizzled: every global load is a coalesced 64-lane x 16B unit.
__global__ __launch_bounds__(256, 3)
void attn_kernel(const float* __restrict__ q,
                 const uint4* __restrict__ ksw,
                 const uint4* __restrict__ vsw,
                 float* __restrict__ out, float sc2 /* bf16(1/sqrt(D)) * log2(e) */) {
    const int lane = threadIdx.x & 63;
    const int wave = threadIdx.x >> 6;
    const int l31  = lane & 31;
    const int hb   = lane >> 5;
    const int qt = (int)(gridDim.x - 1) - (int)blockIdx.x;   // longest blocks dispatch first
    const int g = blockIdx.y, b = blockIdx.z;
    const int h  = g * 4 + wave;
    const int q0 = qt * 32;
    const int tb = b * SS;

    // Q fragments (B operand of S^T): lane holds Q[q=l31][d = 16s + 8hb + j] (once per wave)
    short8 qf[8];
    const float* qp = q + ((size_t)(tb + q0 + l31) * HH + h) * DD;
    #pragma unroll
    for (int s = 0; s < 8; ++s) {
        int d0 = s * 16 + hb * 8;
        float4 f0 = *(const float4*)(qp + d0);
        float4 f1 = *(const float4*)(qp + d0 + 4);
        FragU fr;
        fr.u[0] = pack_bf16x2(f0.x, f0.y); fr.u[1] = pack_bf16x2(f0.z, f0.w);
        fr.u[2] = pack_bf16x2(f1.x, f1.y); fr.u[3] = pack_bf16x2(f1.z, f1.w);
        qf[s] = fr.s8;
    }

    floatx16 oacc[4] = {};            // O^T: 4 d-tiles of 32, col q = l31
    float m = -__builtin_inff(), l = 0.f;

    const uint4* kpl = ksw + (size_t)(b * GG + g) * (32 * 8 * 64);
    const uint4* vpl = vsw + (size_t)(b * GG + g) * (32 * 8 * 64);

    for (int kt = 0; kt <= qt; ++kt) {
        const uint4* kt_k = kpl + kt * 512 + lane;
        const uint4* kt_v = vpl + kt * 512 + lane;
        // S^T tile: A = K (m=key=l31, k=d chunk), B = Q^T
        floatx16 st = {};
        #pragma unroll
        for (int s = 0; s < 8; ++s) {
            FragU kf; kf.u4 = kt_k[s * 64];
            st = __builtin_amdgcn_mfma_f32_32x32x16_bf16(kf.s8, qf[s], st, 0, 0, 0);
        }
        // online softmax over keys (rows of S^T); per-lane q = l31, 16 keys here + 16 in lane^32
        float e[16], tmax = -__builtin_inff();
        #pragma unroll
        for (int r = 0; r < 16; ++r) {
            float val = st[r] * sc2;                       // exp2 domain
            if (kt == qt) {
                int row = (r & 3) + 8 * (r >> 2) + 4 * hb; // key_local
                if (row > l31) val = -__builtin_inff();    // causal mask
            }
            e[r] = val;
            tmax = fmaxf(tmax, val);
        }
        tmax = fmaxf(tmax, __shfl_xor(tmax, 32));
        const float mnew  = fmaxf(m, tmax);
        const float alpha = exp2f(m - mnew);
        m = mnew;
        float p[16], psum = 0.f;
        #pragma unroll
        for (int r = 0; r < 16; ++r) { p[r] = exp2f(e[r] - mnew); psum += p[r]; }
        psum += __shfl_xor(psum, 32);
        l = l * alpha + psum;
        #pragma unroll
        for (int t = 0; t < 4; ++t)
            #pragma unroll
            for (int r = 0; r < 16; ++r) oacc[t][r] *= alpha;
        // P -> bf16 pairs; cross-half swap builds B-operand (P^T) k-chunks
        unsigned pk[8], px[8];
        #pragma unroll
        for (int u2 = 0; u2 < 8; ++u2) pk[u2] = pack_bf16x2(p[2*u2], p[2*u2+1]);
        #pragma unroll
        for (int u2 = 0; u2 < 8; ++u2) px[u2] = (unsigned)__shfl_xor((int)pk[u2], 32);
        // O^T += V^T * P^T  (two k-steps of 16 keys, 4 d-tiles)
        #pragma unroll
        for (int s2 = 0; s2 < 2; ++s2) {
            FragU pf;
            if (hb == 0) { pf.u[0]=pk[4*s2  ]; pf.u[1]=pk[4*s2+1]; pf.u[2]=px[4*s2  ]; pf.u[3]=px[4*s2+1]; }
            else         { pf.u[0]=px[4*s2+2]; pf.u[1]=px[4*s2+3]; pf.u[2]=pk[4*s2+2]; pf.u[3]=pk[4*s2+3]; }
            #pragma unroll
            for (int t = 0; t < 4; ++t) {
                FragU vf; vf.u4 = kt_v[(t * 2 + s2) * 64];
                oacc[t] = __builtin_amdgcn_mfma_f32_32x32x16_bf16(vf.s8, pf.s8, oacc[t], 0, 0, 0);
            }
        }
    }
    // epilogue: normalize (state and O^T both keyed by q = l31 -> pure per-lane) and store
    const float inv_l = 1.f / l;
    float* op = out + ((size_t)(tb + q0 + l31) * HH + h) * DD;
    #pragma unroll
    for (int t = 0; t < 4; ++t) {
        #pragma unroll
        for (int grp = 0; grp < 4; ++grp) {
            float4 o4;
            o4.x = oacc[t][grp*4+0] * inv_l; o4.y = oacc[t][grp*4+1] * inv_l;
            o4.z = oacc[t][grp*4+2] * inv_l; o4.w = oacc[t][grp*4+3] * inv_l;
            *(float4*)(op + t * 32 + grp * 8 + hb * 4) = o4;  // d = 32t + 8grp + 4hb + 0..3
        }
    }
}

extern "C" void kernel_launch(void* const* d_in, const int* in_sizes, int n_in,
                              void* d_out, int out_size, void* d_ws, size_t ws_size,
                              hipStream_t stream) {
    const float* q     = (const float*)d_in[0];
    const float* k     = (const float*)d_in[1];
    const float* v     = (const float*)d_in[2];
    const float* kc_in = (const float*)d_in[3];
    const float* vc_in = (const float*)d_in[4];
    const int*   slot  = (const int*)d_in[5];

    float* o_out  = (float*)d_out;                               // [4096][4096]
    float* kc_out = o_out + (size_t)NTOK * HH * DD;              // [32][256][8][128]
    float* vc_out = kc_out + CACHE_ELEMS;

    uint4* ksw = (uint4*)d_ws;                                   // 8.4 MB
    uint4* vsw = ksw + (size_t)BB * GG * 32 * 8 * 64;            // 8.4 MB

    // scale = f32(bf16(1/sqrt(D))), folded with log2(e) for exp2-domain softmax
    float sc = 1.0f / sqrtf((float)DD);
    unsigned u; memcpy(&u, &sc, 4);
    u = (u + 0x7FFFu + ((u >> 16) & 1u)) & 0xFFFF0000u;
    memcpy(&sc, &u, 4);
    const float sc2 = sc * 1.44269504088896340736f;

    swizzle_k<<<dim3(32, GG, BB), 256, 0, stream>>>(k, ksw);
    swizzle_v<<<dim3(32, GG, BB), 256, 0, stream>>>(v, vsw);
    copy_cache<<<(int)(CACHE_ELEMS / 4 / 256), 256, 0, stream>>>((const float4*)kc_in, (float4*)kc_out);
    copy_cache<<<(int)(CACHE_ELEMS / 4 / 256), 256, 0, stream>>>((const float4*)vc_in, (float4*)vc_out);
    scatter_kernel<<<NTOK, 256, 0, stream>>>(k, v, slot, kc_out, vc_out);
    attn_kernel<<<dim3(SS / 32, GG, BB), 256, 0, stream>>>(q, ksw, vsw, o_out, sc2);
}

// Round 3
// 367.316 us; speedup vs baseline: 1.4902x; 1.2586x over previous
//
#include <hip/hip_runtime.h>
#include <math.h>
#include <string.h>

// Problem constants (from reference)
#define BB 4
#define SS 1024
#define HH 32
#define GG 8       // kv heads
#define DD 128
#define NTOK (BB*SS)
#define NBLK 32
#define BLKSZ 256
#define CACHE_ELEMS ((size_t)NBLK*BLKSZ*GG*DD)   // 8.39M f32 per cache

typedef __attribute__((ext_vector_type(8)))  short  short8;   // 8 bf16 = 4 VGPRs (MFMA A/B operand)
typedef __attribute__((ext_vector_type(16))) float  floatx16; // MFMA C/D

union FragU { unsigned u[4]; uint4 u4; short8 s8; };

typedef __attribute__((address_space(3))) void  lds_void;
typedef __attribute__((address_space(1))) const void glb_void;

// round-to-nearest-even f32 -> bf16, packed pair
__device__ __forceinline__ unsigned pack_bf16x2(float a, float b) {
    unsigned ua = __builtin_bit_cast(unsigned, a);
    unsigned ub = __builtin_bit_cast(unsigned, b);
    ua = (ua + 0x7FFFu + ((ua >> 16) & 1u)) >> 16;
    ub = (ub + 0x7FFFu + ((ub >> 16) & 1u)) & 0xFFFF0000u;
    return ua | ub;
}

// ---------------- prepass: K and V -> fragment-swizzled bf16 (fused) ----------------
// K unit (16B) index: (((b*G + g)*32 + kt)*8 + s)*64 + lane
//   content: bf16 K[b*S + kt*32 + (lane&31)][g][s*16 + (lane>>5)*8 + 0..7]
// V unit index: (((b*G + g)*32 + kt)*8 + (t4*2 + s2))*64 + lane
//   content: bf16 pairs of V[b*S + kt*32 + s2*16 + (lane>>5)*8 + j][g][t4*32 + (lane&31)]
__global__ void swizzle_kv(const float* __restrict__ k, const float* __restrict__ v,
                           uint4* __restrict__ ksw, uint4* __restrict__ vsw) {
    __shared__ float lds[32 * 132];
    const int t = threadIdx.x;
    const int kt = blockIdx.x, gy = blockIdx.y, b = blockIdx.z;
    const int isv = gy >> 3, g = gy & 7;
    const float* sp = (isv ? v : k) + ((size_t)(b * SS + kt * 32) * GG + g) * DD;
    #pragma unroll
    for (int i = 0; i < 4; ++i) {
        int u = t + 256 * i;                  // 1024 float4 units: row = u>>5, c4 = u&31
        int row = u >> 5, c4 = u & 31;
        float4 f = *(const float4*)(sp + (size_t)row * (GG * DD) + c4 * 4);
        float* lp = &lds[row * 132 + c4 * 4];
        lp[0] = f.x; lp[1] = f.y; lp[2] = f.z; lp[3] = f.w;
    }
    __syncthreads();
    const int lane = t & 63, hb = lane >> 5, l31 = lane & 31;
    const size_t tbase = ((size_t)(b * GG + g) * 32 + kt) * 8;
    if (!isv) {
        #pragma unroll
        for (int i = 0; i < 2; ++i) {
            int s = (t >> 6) + 4 * i;             // s in 0..7
            const float* lp = &lds[l31 * 132 + s * 16 + hb * 8];
            uint4 o;
            o.x = pack_bf16x2(lp[0], lp[1]); o.y = pack_bf16x2(lp[2], lp[3]);
            o.z = pack_bf16x2(lp[4], lp[5]); o.w = pack_bf16x2(lp[6], lp[7]);
            ksw[(tbase + s) * 64 + lane] = o;
        }
    } else {
        #pragma unroll
        for (int i = 0; i < 2; ++i) {
            int f8 = (t >> 6) + 4 * i;            // t4*2 + s2, 0..7
            int t4 = f8 >> 1, s2 = f8 & 1;
            int keyb = s2 * 16 + hb * 8;
            int d = t4 * 32 + l31;
            uint4 o;
            o.x = pack_bf16x2(lds[(keyb + 0) * 132 + d], lds[(keyb + 1) * 132 + d]);
            o.y = pack_bf16x2(lds[(keyb + 2) * 132 + d], lds[(keyb + 3) * 132 + d]);
            o.z = pack_bf16x2(lds[(keyb + 4) * 132 + d], lds[(keyb + 5) * 132 + d]);
            o.w = pack_bf16x2(lds[(keyb + 6) * 132 + d], lds[(keyb + 7) * 132 + d]);
            vsw[(tbase + f8) * 64 + lane] = o;
        }
    }
}

// ---------------- cache copy (both caches, one launch) ----------------
__global__ void copy_cache2(const float4* __restrict__ s0, const float4* __restrict__ s1,
                            float4* __restrict__ d0, float4* __restrict__ d1) {
    const size_t half = CACHE_ELEMS / 4;
    size_t i = (size_t)blockIdx.x * 256 + threadIdx.x;
    if (i < half) d0[i] = s0[i];
    else          d1[i - half] = s1[i - half];
}

// ---------------- cache scatter ----------------
__global__ void scatter_kernel(const float* __restrict__ k, const float* __restrict__ v,
                               const int* __restrict__ slot_mapping,
                               float* __restrict__ kco, float* __restrict__ vco) {
    const int tok = blockIdx.x, c = threadIdx.x;  // 256 float4 per token row (G*D = 1024 f32)
    const int slot = slot_mapping[tok];
    if (slot < 0 || slot >= NBLK * BLKSZ) return;
    float4 kf = ((const float4*)(k + (size_t)tok * 1024))[c];
    float4 vf = ((const float4*)(v + (size_t)tok * 1024))[c];
    ((float4*)(kco + (size_t)slot * 1024))[c] = kf;
    ((float4*)(vco + (size_t)slot * 1024))[c] = vf;
}

// ---------------- fused causal GQA flash attention ----------------
// block = 4 waves = 4 q-heads of one kv group; wave handles 32 q rows.
// K/V tiles staged once per BLOCK in LDS (4x traffic cut vs per-wave loads),
// double-buffered: prefetch tile kt+1 via global_load_lds right after the
// barrier; the softmax+MFMA phase hides the load latency.
__global__ __launch_bounds__(256, 3)
void attn_kernel(const float* __restrict__ q,
                 const uint4* __restrict__ ksw,
                 const uint4* __restrict__ vsw,
                 float* __restrict__ out, float sc2 /* bf16(1/sqrt(D)) * log2(e) */) {
    __shared__ uint4 sm[2][16][64];               // [buf][row: 0-7 K, 8-15 V][lane], 32 KB
    const int lane = threadIdx.x & 63;
    const int wave = threadIdx.x >> 6;
    const int l31  = lane & 31;
    const int hb   = lane >> 5;
    const int qt = (int)(gridDim.x - 1) - (int)blockIdx.x;   // longest blocks dispatch first
    const int g = blockIdx.y, b = blockIdx.z;
    const int h  = g * 4 + wave;
    const int q0 = qt * 32;
    const int tb = b * SS;

    const uint4* kpl = ksw + (size_t)(b * GG + g) * (32 * 8 * 64);
    const uint4* vpl = vsw + (size_t)(b * GG + g) * (32 * 8 * 64);

    // stage tile 0 into buffer 0: wave w stages K rows {2w,2w+1} and V rows {2w,2w+1}
    #pragma unroll
    for (int i = 0; i < 2; ++i) {
        int row = wave * 2 + i;
        __builtin_amdgcn_global_load_lds((glb_void*)(kpl + row * 64 + lane),
                                         (lds_void*)(&sm[0][row][0]),     16, 0, 0);
        __builtin_amdgcn_global_load_lds((glb_void*)(vpl + row * 64 + lane),
                                         (lds_void*)(&sm[0][8 + row][0]), 16, 0, 0);
    }

    // Q fragments (B operand of S^T): lane holds Q[q=l31][d = 16s + 8hb + j]
    short8 qf[8];
    const float* qp = q + ((size_t)(tb + q0 + l31) * HH + h) * DD;
    #pragma unroll
    for (int s = 0; s < 8; ++s) {
        int d0 = s * 16 + hb * 8;
        float4 f0 = *(const float4*)(qp + d0);
        float4 f1 = *(const float4*)(qp + d0 + 4);
        FragU fr;
        fr.u[0] = pack_bf16x2(f0.x, f0.y); fr.u[1] = pack_bf16x2(f0.z, f0.w);
        fr.u[2] = pack_bf16x2(f1.x, f1.y); fr.u[3] = pack_bf16x2(f1.z, f1.w);
        qf[s] = fr.s8;
    }

    floatx16 oacc[4] = {};            // O^T: 4 d-tiles of 32, col q = l31
    float m = -__builtin_inff(), l = 0.f;

    __syncthreads();                  // tile 0 resident

    for (int kt = 0; kt <= qt; ++kt) {
        const int cur = kt & 1;
        if (kt < qt) {                // prefetch tile kt+1 into the other buffer
            const uint4* gk = kpl + (kt + 1) * 512;
            const uint4* gv = vpl + (kt + 1) * 512;
            #pragma unroll
            for (int i = 0; i < 2; ++i) {
                int row = wave * 2 + i;
                __builtin_amdgcn_global_load_lds((glb_void*)(gk + row * 64 + lane),
                                                 (lds_void*)(&sm[cur ^ 1][row][0]),     16, 0, 0);
                __builtin_amdgcn_global_load_lds((glb_void*)(gv + row * 64 + lane),
                                                 (lds_void*)(&sm[cur ^ 1][8 + row][0]), 16, 0, 0);
            }
        }
        // S^T tile: A = K (m=key=l31, k=d chunk), B = Q^T — two independent MFMA chains
        floatx16 st0 = {}, st1 = {};
        #pragma unroll
        for (int s = 0; s < 4; ++s) {
            FragU ka; ka.u4 = sm[cur][s][lane];
            st0 = __builtin_amdgcn_mfma_f32_32x32x16_bf16(ka.s8, qf[s], st0, 0, 0, 0);
            FragU kb; kb.u4 = sm[cur][s + 4][lane];
            st1 = __builtin_amdgcn_mfma_f32_32x32x16_bf16(kb.s8, qf[s + 4], st1, 0, 0, 0);
        }
        // online softmax over keys; per-lane q = l31, 16 keys here + 16 in lane^32
        float e[16];
        #pragma unroll
        for (int r = 0; r < 16; ++r) {
            float val = (st0[r] + st1[r]) * sc2;           // exp2 domain
            if (kt == qt) {
                int row = (r & 3) + 8 * (r >> 2) + 4 * hb; // key_local
                if (row > l31) val = -__builtin_inff();    // causal mask
            }
            e[r] = val;
        }
        float tr[8];
        #pragma unroll
        for (int i = 0; i < 8; ++i) tr[i] = fmaxf(e[i], e[i + 8]);
        #pragma unroll
        for (int i = 0; i < 4; ++i) tr[i] = fmaxf(tr[i], tr[i + 4]);
        tr[0] = fmaxf(tr[0], tr[2]); tr[1] = fmaxf(tr[1], tr[3]);
        float tmax = fmaxf(tr[0], tr[1]);
        tmax = fmaxf(tmax, __shfl_xor(tmax, 32));
        const float mnew  = fmaxf(m, tmax);
        const float alpha = exp2f(m - mnew);
        float p[16];
        #pragma unroll
        for (int r = 0; r < 16; ++r) p[r] = exp2f(e[r] - mnew);
        float sr[8];
        #pragma unroll
        for (int i = 0; i < 8; ++i) sr[i] = p[i] + p[i + 8];
        #pragma unroll
        for (int i = 0; i < 4; ++i) sr[i] += sr[i + 4];
        float psum = (sr[0] + sr[1]) + (sr[2] + sr[3]);
        psum += __shfl_xor(psum, 32);
        if (__any(tmax > m)) {                 // rescale only when some lane's max moved
            #pragma unroll
            for (int t = 0; t < 4; ++t)
                #pragma unroll
                for (int r = 0; r < 16; ++r) oacc[t][r] *= alpha;
        }
        l = l * alpha + psum;
        m = mnew;
        // P -> bf16 pairs; cross-half swap builds B-operand (P^T) k-chunks
        unsigned pk[8], px[8];
        #pragma unroll
        for (int u2 = 0; u2 < 8; ++u2) pk[u2] = pack_bf16x2(p[2*u2], p[2*u2+1]);
        #pragma unroll
        for (int u2 = 0; u2 < 8; ++u2) px[u2] = (unsigned)__shfl_xor((int)pk[u2], 32);
        // O^T += V^T * P^T  (two k-steps of 16 keys, 4 d-tiles)
        #pragma unroll
        for (int s2 = 0; s2 < 2; ++s2) {
            FragU pf;
            if (hb == 0) { pf.u[0]=pk[4*s2  ]; pf.u[1]=pk[4*s2+1]; pf.u[2]=px[4*s2  ]; pf.u[3]=px[4*s2+1]; }
            else         { pf.u[0]=px[4*s2+2]; pf.u[1]=px[4*s2+3]; pf.u[2]=pk[4*s2+2]; pf.u[3]=pk[4*s2+3]; }
            #pragma unroll
            for (int t = 0; t < 4; ++t) {
                FragU vf; vf.u4 = sm[cur][8 + t * 2 + s2][lane];
                oacc[t] = __builtin_amdgcn_mfma_f32_32x32x16_bf16(vf.s8, pf.s8, oacc[t], 0, 0, 0);
            }
        }
        __syncthreads();   // all waves done with sm[cur]; prefetch into sm[cur^1] drained
    }
    // epilogue: normalize (state and O^T both keyed by q = l31 -> pure per-lane) and store
    const float inv_l = 1.f / l;
    float* op = out + ((size_t)(tb + q0 + l31) * HH + h) * DD;
    #pragma unroll
    for (int t = 0; t < 4; ++t) {
        #pragma unroll
        for (int grp = 0; grp < 4; ++grp) {
            float4 o4;
            o4.x = oacc[t][grp*4+0] * inv_l; o4.y = oacc[t][grp*4+1] * inv_l;
            o4.z = oacc[t][grp*4+2] * inv_l; o4.w = oacc[t][grp*4+3] * inv_l;
            *(float4*)(op + t * 32 + grp * 8 + hb * 4) = o4;  // d = 32t + 8grp + 4hb + 0..3
        }
    }
}

extern "C" void kernel_launch(void* const* d_in, const int* in_sizes, int n_in,
                              void* d_out, int out_size, void* d_ws, size_t ws_size,
                              hipStream_t stream) {
    const float* q     = (const float*)d_in[0];
    const float* k     = (const float*)d_in[1];
    const float* v     = (const float*)d_in[2];
    const float* kc_in = (const float*)d_in[3];
    const float* vc_in = (const float*)d_in[4];
    const int*   slot  = (const int*)d_in[5];

    float* o_out  = (float*)d_out;                               // [4096][4096]
    float* kc_out = o_out + (size_t)NTOK * HH * DD;              // [32][256][8][128]
    float* vc_out = kc_out + CACHE_ELEMS;

    uint4* ksw = (uint4*)d_ws;                                   // 8.4 MB
    uint4* vsw = ksw + (size_t)BB * GG * 32 * 8 * 64;            // 8.4 MB

    // scale = f32(bf16(1/sqrt(D))), folded with log2(e) for exp2-domain softmax
    float sc = 1.0f / sqrtf((float)DD);
    unsigned u; memcpy(&u, &sc, 4);
    u = (u + 0x7FFFu + ((u >> 16) & 1u)) & 0xFFFF0000u;
    memcpy(&sc, &u, 4);
    const float sc2 = sc * 1.44269504088896340736f;

    swizzle_kv<<<dim3(32, GG * 2, BB), 256, 0, stream>>>(k, v, ksw, vsw);
    copy_cache2<<<(int)(CACHE_ELEMS / 4 / 256) * 2, 256, 0, stream>>>(
        (const float4*)kc_in, (const float4*)vc_in, (float4*)kc_out, (float4*)vc_out);
    scatter_kernel<<<NTOK, 256, 0, stream>>>(k, v, slot, kc_out, vc_out);
    attn_kernel<<<dim3(SS / 32, GG, BB), 256, 0, stream>>>(q, ksw, vsw, o_out, sc2);
}